// Round 5
// baseline (669.328 us; speedup 1.0000x reference)
//
#include <hip/hip_runtime.h>

#define N_NODES 50000
#define N_EDGES 500000
#define D_NODE 64
#define D_EDGE 32
#define MSG_DIM 160
#define HID_DIM 224
#define ALPHA 0.01f

#define FNB 16          // nodes per fused block (50000 = 3125 * 16 exactly)
#define NBKT 3125       // node buckets = fused grid size
#define A_STRIDE 168    // 160 + 8 pad (shorts) -> conflict-free b128 frag reads
#define MACC_STRIDE 165 // floats; odd stride spreads ds_add banks
#define CURSOR_PAD 16   // ints per bucket cursor (64B line -> no line contention)
#define CVT_BLKS 3200   // ceil(818944/256)
#define HIST_BLKS 1954  // ceil(500000/256)

typedef unsigned short u16;
typedef short short8 __attribute__((ext_vector_type(8)));
typedef float float4v __attribute__((ext_vector_type(4)));

static __device__ __forceinline__ u16 f2bf(float f) {
    unsigned int u = __float_as_uint(f);
    u += 0x7fffu + ((u >> 16) & 1u);   // round-to-nearest-even
    return (u16)(u >> 16);
}

// fused: bf16 conversion of h_n/W_msg/W_hid (blocks 0..3199) + dst histogram
// over per-node counters (blocks 3200..5153)
__global__ __launch_bounds__(256) void cvt_hist(const float* __restrict__ h_n,
                                                const float* __restrict__ W_msg,
                                                const float* __restrict__ W_hid,
                                                const int* __restrict__ dst,
                                                u16* __restrict__ hn_bf,
                                                u16* __restrict__ Wm_bf,
                                                u16* __restrict__ Wh_bf,
                                                int* __restrict__ cnt) {
    const int b = blockIdx.x;
    if (b < CVT_BLKS) {
        int i = b * 256 + threadIdx.x;
        const float* in; u16* outp; int j;
        if (i < 800000)      { in = h_n;   outp = hn_bf; j = i; }
        else if (i < 806400) { in = W_msg; outp = Wm_bf; j = i - 800000; }
        else if (i < 818944) { in = W_hid; outp = Wh_bf; j = i - 806400; }
        else return;
        float4 v = reinterpret_cast<const float4*>(in)[j];
        ushort4 o;
        o.x = f2bf(v.x); o.y = f2bf(v.y); o.z = f2bf(v.z); o.w = f2bf(v.w);
        reinterpret_cast<ushort4*>(outp)[j] = o;
    } else {
        int e = (b - CVT_BLKS) * 256 + threadIdx.x;
        if (e < N_EDGES) atomicAdd(&cnt[dst[e]], 1);   // 50k counters: low line contention
    }
}

// single-block scan: per-node cnt -> per-bucket (16 nodes) exclusive offsets.
// writes bkt_ptr[0..NBKT] and padded cursor copies for the scatter.
__global__ __launch_bounds__(1024) void scan_kernel(const int* __restrict__ cnt,
                                                    int* __restrict__ bkt_ptr,
                                                    int* __restrict__ cursor) {
    __shared__ int sd[1024];
    const int t = threadIdx.x;
    int bsum[4]; int T = 0;
#pragma unroll
    for (int i = 0; i < 4; ++i) {
        const int bk = t * 4 + i;
        int s = 0;
        if (bk < NBKT) {
            const int base = bk * FNB;
            for (int j = 0; j < FNB; ++j) s += cnt[base + j];
        }
        bsum[i] = s; T += s;
    }
    sd[t] = T;
    __syncthreads();
    for (int off = 1; off < 1024; off <<= 1) {      // Hillis-Steele inclusive
        int v = (t >= off) ? sd[t - off] : 0;
        __syncthreads();
        sd[t] += v;
        __syncthreads();
    }
    int run = sd[t] - T;                            // exclusive prefix
#pragma unroll
    for (int i = 0; i < 4; ++i) {
        const int bk = t * 4 + i;
        if (bk < NBKT) {
            bkt_ptr[bk] = run;
            cursor[bk * CURSOR_PAD] = run;
            run += bsum[i];
        }
    }
    if (t == 0) bkt_ptr[NBKT] = N_EDGES;
}

// scatter edges into bucket-grouped order (random within bucket -> low
// same-address collision for the fused kernel's LDS atomics)
__global__ __launch_bounds__(256) void scatter_kernel(const int* __restrict__ src,
                                                      const int* __restrict__ dst,
                                                      int* __restrict__ cursor,
                                                      int* __restrict__ eid_s,
                                                      int* __restrict__ src_s,
                                                      int* __restrict__ dst_s) {
    int e = blockIdx.x * 256 + threadIdx.x;
    if (e < N_EDGES) {
        int d = dst[e];
        int p = atomicAdd(&cursor[(d >> 4) * CURSOR_PAD], 1);
        eid_s[p] = e;
        src_s[p] = src[e];
        dst_s[p] = d;
    }
}

// ---------------- fused edge-message + reduce + node-update kernel ----------------
// Block b owns nodes [16b, 16b+16) = bucketed edges [bkt_ptr[b], bkt_ptr[b+1]).
// Phase 1: 64-edge tiles -> transposed MFMA C[f][e] -> direct per-lane LDS
//          atomicAdd into m_acc (no shuffle scan, no global atomics).
// Phase 2: repack m_acc to bf16 in LDS, update GEMM with W_hid, store out.
__global__ __launch_bounds__(256) void fused_kernel(
    const u16* __restrict__ hn_bf, const float* __restrict__ h_e,
    const int* __restrict__ src_s, const int* __restrict__ dst_s,
    const int* __restrict__ eid_s, const int* __restrict__ bkt_ptr,
    const u16* __restrict__ Wm_bf, const float* __restrict__ b_msg,
    const u16* __restrict__ Wh_bf, const float* __restrict__ b_hid,
    float* __restrict__ out)
{
    __shared__ alignas(16) u16 X_lds[64 * A_STRIDE];        // 21504 B (reused in ph2)
    __shared__ alignas(16) float m_acc[FNB * MACC_STRIDE];  // 10560 B
    __shared__ int dst_lds[64];                             //   256 B  -> ~32.3 KB

    const int tid = threadIdx.x;
    const int n0 = blockIdx.x * FNB;
    const int p_begin = bkt_ptr[blockIdx.x];
    const int p_end   = bkt_ptr[blockIdx.x + 1];

    for (int i = tid; i < FNB * MACC_STRIDE; i += 256) m_acc[i] = 0.f;
    __syncthreads();   // zeros visible before any ds_add

    const int wave = tid >> 6, lane = tid & 63;
    const int qd = lane >> 4, l15 = lane & 15;

    // ---------------- phase 1: edge tiles ----------------
    for (int p0 = p_begin; p0 < p_end; p0 += 64) {
        {   // stage 64 bucketed edges x 160 bf16 (4 threads per edge)
            const int e_loc = tid >> 2, j = tid & 3;
            int pp = p0 + e_loc; if (pp > p_end - 1) pp = p_end - 1;
            const int s = src_s[pp], d = dst_s[pp], eo = eid_s[pp];
            if (j == 0) dst_lds[e_loc] = d;
            const uint4* srow = reinterpret_cast<const uint4*>(hn_bf + (size_t)s * D_NODE);
            const uint4* drow = reinterpret_cast<const uint4*>(hn_bf + (size_t)d * D_NODE);
            uint4* Arow = reinterpret_cast<uint4*>(&X_lds[e_loc * A_STRIDE]);
            Arow[j * 2]     = srow[j * 2];        // bf16 [0,64): h_n[src]
            Arow[j * 2 + 1] = srow[j * 2 + 1];
            Arow[8 + j * 2]     = drow[j * 2];    // bf16 [64,128): h_n[dst]
            Arow[8 + j * 2 + 1] = drow[j * 2 + 1];
            const float4* he = reinterpret_cast<const float4*>(h_e + (size_t)eo * D_EDGE);
            float4 p = he[j * 2], q = he[j * 2 + 1];
            ushort4 lo, hi;
            lo.x = f2bf(p.x); lo.y = f2bf(p.y); lo.z = f2bf(p.z); lo.w = f2bf(p.w);
            hi.x = f2bf(q.x); hi.y = f2bf(q.y); hi.z = f2bf(q.z); hi.w = f2bf(q.w);
            ushort4* Aus = reinterpret_cast<ushort4*>(Arow);
            Aus[32 + j * 2]     = lo;             // bf16 [128,160): h_e
            Aus[32 + j * 2 + 1] = hi;
        }
        __syncthreads();

        short8 x_frag[5];
#pragma unroll
        for (int ks = 0; ks < 5; ++ks)
            x_frag[ks] = *reinterpret_cast<const short8*>(
                &X_lds[(wave * 16 + l15) * A_STRIDE + ks * 32 + qd * 8]);

        const int rel = dst_lds[wave * 16 + l15] - n0;   // in [0,16) by bucketing
        const bool ok = (p0 + wave * 16 + l15) < p_end;

        for (int c = 0; c < 10; ++c) {            // 10 chunks of 16 features
            const int fbase = c * 16;
            float4v acc = {0.f, 0.f, 0.f, 0.f};
#pragma unroll
            for (int ks = 0; ks < 5; ++ks) {
                short8 w = *reinterpret_cast<const short8*>(
                    Wm_bf + (size_t)(fbase + l15) * MSG_DIM + ks * 32 + qd * 8);
                acc = __builtin_amdgcn_mfma_f32_16x16x32_bf16(w, x_frag[ks], acc, 0, 0, 0);
            }
            const float4 bias = *reinterpret_cast<const float4*>(b_msg + fbase + qd * 4);
            float v0 = acc[0] + bias.x, v1 = acc[1] + bias.y,
                  v2 = acc[2] + bias.z, v3 = acc[3] + bias.w;
            v0 = v0 > 0.f ? v0 : ALPHA * v0;  v1 = v1 > 0.f ? v1 : ALPHA * v1;
            v2 = v2 > 0.f ? v2 : ALPHA * v2;  v3 = v3 > 0.f ? v3 : ALPHA * v3;
            if (ok) {   // direct LDS atomics: ~2-3-way collisions (random order)
                float* row = &m_acc[rel * MACC_STRIDE + fbase + qd * 4];
                atomicAdd(row + 0, v0);
                atomicAdd(row + 1, v1);
                atomicAdd(row + 2, v2);
                atomicAdd(row + 3, v3);
            }
        }
        __syncthreads();   // ds_adds + x_frag reads done before restage
    }

    // ---------------- phase 2: repack m_acc -> bf16 LDS, then update GEMM ----
    u16* Xb = X_lds;       // reuse (phase-1 reads complete)
    for (int i = tid; i < FNB * MSG_DIM; i += 256) {
        const int node = i / MSG_DIM, f = i - node * MSG_DIM;
        Xb[node * A_STRIDE + f] = f2bf(m_acc[node * MACC_STRIDE + f]);
    }
    __syncthreads();

    const int node = n0 + l15;                     // exact: no bounds check needed
    short8 b_frag[7];
#pragma unroll
    for (int ks = 0; ks < 5; ++ks)                 // k in [0,160): m_sum (bf16)
        b_frag[ks] = *reinterpret_cast<const short8*>(
            &Xb[l15 * A_STRIDE + ks * 32 + qd * 8]);
#pragma unroll
    for (int ks = 5; ks < 7; ++ks)                 // k in [160,224): h_n (bf16)
        b_frag[ks] = *reinterpret_cast<const short8*>(
            hn_bf + (size_t)node * D_NODE + (ks - 5) * 32 + qd * 8);

    for (int c = wave; c < 14; c += 4) {           // waves split feature chunks
        float4v acc = {0.f, 0.f, 0.f, 0.f};
#pragma unroll
        for (int ks = 0; ks < 7; ++ks) {
            short8 a = *reinterpret_cast<const short8*>(
                Wh_bf + (size_t)(c * 16 + l15) * HID_DIM + ks * 32 + qd * 8);
            acc = __builtin_amdgcn_mfma_f32_16x16x32_bf16(a, b_frag[ks], acc, 0, 0, 0);
        }
        const float4 bias = *reinterpret_cast<const float4*>(b_hid + c * 16 + qd * 4);
        float v0 = acc[0] + bias.x, v1 = acc[1] + bias.y,
              v2 = acc[2] + bias.z, v3 = acc[3] + bias.w;
        v0 = v0 > 0.f ? v0 : ALPHA * v0;  v1 = v1 > 0.f ? v1 : ALPHA * v1;
        v2 = v2 > 0.f ? v2 : ALPHA * v2;  v3 = v3 > 0.f ? v3 : ALPHA * v3;
        float4 o; o.x = v0; o.y = v1; o.z = v2; o.w = v3;
        *reinterpret_cast<float4*>(&out[(size_t)node * HID_DIM + c * 16 + qd * 4]) = o;
    }
}

extern "C" void kernel_launch(void* const* d_in, const int* in_sizes, int n_in,
                              void* d_out, int out_size, void* d_ws, size_t ws_size,
                              hipStream_t stream)
{
    const float* h_n   = (const float*)d_in[0];
    const float* h_e   = (const float*)d_in[1];
    const int*   src   = (const int*)d_in[2];
    const int*   dst   = (const int*)d_in[3];
    const float* W_msg = (const float*)d_in[4];
    const float* b_msg = (const float*)d_in[5];
    const float* W_hid = (const float*)d_in[6];
    const float* b_hid = (const float*)d_in[7];
    float* out = (float*)d_out;

    char* ws = (char*)d_ws;
    u16* hn_bf   = (u16*)(ws + 0);                   //  6,400,000 B
    u16* Wm_bf   = (u16*)(ws + 6400000);             //     51,200 B
    u16* Wh_bf   = (u16*)(ws + 6451200);             //    100,352 B
    int* cnt     = (int*)(ws + 6551552);             //    200,000 B
    int* bkt_ptr = (int*)(ws + 6751552);             //     12,512 B (3126 ints, padded)
    int* cursor  = (int*)(ws + 6764064);             //    200,000 B (3125 x 16 ints)
    int* eid_s   = (int*)(ws + 6964064);             //  2,000,000 B
    int* src_s   = (int*)(ws + 8964064);             //  2,000,000 B
    int* dst_s   = (int*)(ws + 10964064);            //  2,000,000 B  (~13 MB total)

    hipMemsetAsync(cnt, 0, (size_t)N_NODES * sizeof(int), stream);
    cvt_hist<<<CVT_BLKS + HIST_BLKS, 256, 0, stream>>>(
        h_n, W_msg, W_hid, dst, hn_bf, Wm_bf, Wh_bf, cnt);
    scan_kernel<<<1, 1024, 0, stream>>>(cnt, bkt_ptr, cursor);
    scatter_kernel<<<HIST_BLKS, 256, 0, stream>>>(src, dst, cursor, eid_s, src_s, dst_s);
    fused_kernel<<<NBKT, 256, 0, stream>>>(
        hn_bf, h_e, src_s, dst_s, eid_s, bkt_ptr, Wm_bf, b_msg, Wh_bf, b_hid, out);
}

// Round 6
// 303.195 us; speedup vs baseline: 2.2076x; 2.2076x over previous
//
#include <hip/hip_runtime.h>

#define N_NODES 50000
#define N_EDGES 500000
#define D_NODE 64
#define D_EDGE 32
#define MSG_DIM 160
#define HID_DIM 224
#define ALPHA 0.01f

#define FNB 16          // nodes per fused block (50000 = 3125 * 16 exactly)
#define NBKT 3125       // node buckets = fused grid size
#define A_STRIDE 168    // 160 + 8 pad (shorts) -> conflict-free b128 frag reads
#define MT_STRIDE 72    // 64 edges + 8 pad (shorts), per-wave transpose buffer
#define CURSOR_PAD 16   // ints per bucket cursor (64B line -> no line contention)
#define CVT_BLKS 3200   // ceil(818944/256)
#define HIST_BLKS 1954  // ceil(500000/256)

typedef unsigned short u16;
typedef unsigned long long u64;
typedef short short8 __attribute__((ext_vector_type(8)));
typedef float float4v __attribute__((ext_vector_type(4)));

static __device__ __forceinline__ u16 f2bf(float f) {
    unsigned int u = __float_as_uint(f);
    u += 0x7fffu + ((u >> 16) & 1u);   // round-to-nearest-even
    return (u16)(u >> 16);
}

// fused: bf16 conversion of h_n/W_msg/W_hid (blocks 0..3199) + dst histogram
__global__ __launch_bounds__(256) void cvt_hist(const float* __restrict__ h_n,
                                                const float* __restrict__ W_msg,
                                                const float* __restrict__ W_hid,
                                                const int* __restrict__ dst,
                                                u16* __restrict__ hn_bf,
                                                u16* __restrict__ Wm_bf,
                                                u16* __restrict__ Wh_bf,
                                                int* __restrict__ cnt) {
    const int b = blockIdx.x;
    if (b < CVT_BLKS) {
        int i = b * 256 + threadIdx.x;
        const float* in; u16* outp; int j;
        if (i < 800000)      { in = h_n;   outp = hn_bf; j = i; }
        else if (i < 806400) { in = W_msg; outp = Wm_bf; j = i - 800000; }
        else if (i < 818944) { in = W_hid; outp = Wh_bf; j = i - 806400; }
        else return;
        float4 v = reinterpret_cast<const float4*>(in)[j];
        ushort4 o;
        o.x = f2bf(v.x); o.y = f2bf(v.y); o.z = f2bf(v.z); o.w = f2bf(v.w);
        reinterpret_cast<ushort4*>(outp)[j] = o;
    } else {
        int e = (b - CVT_BLKS) * 256 + threadIdx.x;
        if (e < N_EDGES) atomicAdd(&cnt[dst[e]], 1);   // 50k counters: low contention
    }
}

// single-block scan: per-node cnt -> per-bucket (16 nodes) exclusive offsets
__global__ __launch_bounds__(1024) void scan_kernel(const int* __restrict__ cnt,
                                                    int* __restrict__ bkt_ptr,
                                                    int* __restrict__ cursor) {
    __shared__ int sd[1024];
    const int t = threadIdx.x;
    int bsum[4]; int T = 0;
#pragma unroll
    for (int i = 0; i < 4; ++i) {
        const int bk = t * 4 + i;
        int s = 0;
        if (bk < NBKT) {
            const int base = bk * FNB;
            for (int j = 0; j < FNB; ++j) s += cnt[base + j];
        }
        bsum[i] = s; T += s;
    }
    sd[t] = T;
    __syncthreads();
    for (int off = 1; off < 1024; off <<= 1) {      // Hillis-Steele inclusive
        int v = (t >= off) ? sd[t - off] : 0;
        __syncthreads();
        sd[t] += v;
        __syncthreads();
    }
    int run = sd[t] - T;                            // exclusive prefix
#pragma unroll
    for (int i = 0; i < 4; ++i) {
        const int bk = t * 4 + i;
        if (bk < NBKT) {
            bkt_ptr[bk] = run;
            cursor[bk * CURSOR_PAD] = run;
            run += bsum[i];
        }
    }
    if (t == 0) bkt_ptr[NBKT] = N_EDGES;
}

// scatter edges into bucket-grouped order as packed u64 (eid<<34 | dst<<17 | src)
__global__ __launch_bounds__(256) void scatter_kernel(const int* __restrict__ src,
                                                      const int* __restrict__ dst,
                                                      int* __restrict__ cursor,
                                                      u64* __restrict__ pack) {
    int e = blockIdx.x * 256 + threadIdx.x;
    if (e < N_EDGES) {
        int d = dst[e];
        int p = atomicAdd(&cursor[(d >> 4) * CURSOR_PAD], 1);
        pack[p] = ((u64)e << 34) | ((u64)d << 17) | (u64)src[e];
    }
}

// ---------------- fused kernel: msg GEMM -> MFMA-based segment reduce -> update GEMM
// Block b owns nodes [16b,16b+16) = bucketed edges [bkt_ptr[b], bkt_ptr[b+1]).
// No atomics anywhere: reduction is m_acc[16n][16f] += S[16n][64e] x M[64e][16f]
// via two mfma_16x16x32 per chunk, with S the 0/1 dst-selection matrix and
// m_acc persistent in registers across tiles.
__global__ __launch_bounds__(256) void fused_kernel(
    const u16* __restrict__ hn_bf, const float* __restrict__ h_e,
    const u64* __restrict__ pack, const int* __restrict__ bkt_ptr,
    const u16* __restrict__ Wm_bf, const float* __restrict__ b_msg,
    const u16* __restrict__ Wh_bf, const float* __restrict__ b_hid,
    float* __restrict__ out)
{
    __shared__ alignas(16) u16 X_lds[64 * A_STRIDE];        // 21504 B (Xb in ph2)
    __shared__ alignas(16) u16 MT[4 * 16 * MT_STRIDE];      //  9216 B (per-wave)
    __shared__ alignas(16) u16 dst16[64];                   //   128 B  -> ~30.9 KB

    const int tid = threadIdx.x;
    const int n0 = blockIdx.x * FNB;
    const int p_begin = bkt_ptr[blockIdx.x];
    const int p_end   = bkt_ptr[blockIdx.x + 1];

    const int wave = tid >> 6, lane = tid & 63;
    const int qd = lane >> 4, l15 = lane & 15;

    // chunk ownership: wave w owns chunks {w, w+4, w+8} (<10)
    const int nchunk = (wave < 2) ? 3 : 2;
    float biasv[3];
#pragma unroll
    for (int ci = 0; ci < 3; ++ci) {
        const int c = wave + ci * 4;
        biasv[ci] = (c < 10) ? b_msg[c * 16 + l15] : 0.f;
    }
    float4v m_acc[3] = {{0,0,0,0},{0,0,0,0},{0,0,0,0}};
    u16* MTw = &MT[wave * 16 * MT_STRIDE];

    // ---------------- phase 1: edge tiles ----------------
    for (int p0 = p_begin; p0 < p_end; p0 += 64) {
        {   // stage 64 bucketed edges x 160 bf16 (4 threads per edge)
            const int e_loc = tid >> 2, j = tid & 3;
            int pp = p0 + e_loc;
            const bool padE = (pp >= p_end); if (padE) pp = p_end - 1;
            const u64 pk = pack[pp];
            const int s  = (int)(pk & 0x1FFFF);
            const int d  = (int)((pk >> 17) & 0x1FFFF);
            const int eo = (int)(pk >> 34);
            if (j == 0) dst16[e_loc] = padE ? (u16)0xFFFFu : (u16)(d - n0);
            const uint4* srow = reinterpret_cast<const uint4*>(hn_bf + (size_t)s * D_NODE);
            const uint4* drow = reinterpret_cast<const uint4*>(hn_bf + (size_t)d * D_NODE);
            uint4* Arow = reinterpret_cast<uint4*>(&X_lds[e_loc * A_STRIDE]);
            Arow[j * 2]     = srow[j * 2];        // bf16 [0,64): h_n[src]
            Arow[j * 2 + 1] = srow[j * 2 + 1];
            Arow[8 + j * 2]     = drow[j * 2];    // bf16 [64,128): h_n[dst]
            Arow[8 + j * 2 + 1] = drow[j * 2 + 1];
            const float4* he = reinterpret_cast<const float4*>(h_e + (size_t)eo * D_EDGE);
            float4 p = he[j * 2], q = he[j * 2 + 1];
            ushort4 lo, hi;
            lo.x = f2bf(p.x); lo.y = f2bf(p.y); lo.z = f2bf(p.z); lo.w = f2bf(p.w);
            hi.x = f2bf(q.x); hi.y = f2bf(q.y); hi.z = f2bf(q.z); hi.w = f2bf(q.w);
            ushort4* Aus = reinterpret_cast<ushort4*>(Arow);
            Aus[32 + j * 2]     = lo;             // bf16 [128,160): h_e
            Aus[32 + j * 2 + 1] = hi;
        }
        __syncthreads();   // stage visible

        // x-frags for ALL 64 edges (A operand: lane=edge row, k=qd*8+j)
        short8 xf[4][5];
#pragma unroll
        for (int s = 0; s < 4; ++s)
#pragma unroll
            for (int ks = 0; ks < 5; ++ks)
                xf[s][ks] = *reinterpret_cast<const short8*>(
                    &X_lds[(s * 16 + l15) * A_STRIDE + ks * 32 + qd * 8]);

        // selection frags S[n=l15][e=fi*32+qd*8+j] (bf16 1.0 / 0.0)
        short8 a2[2];
#pragma unroll
        for (int fi = 0; fi < 2; ++fi) {
            short8 dv = *reinterpret_cast<const short8*>(&dst16[fi * 32 + qd * 8]);
            short8 t;
#pragma unroll
            for (int j = 0; j < 8; ++j)
                t[j] = (short)(((int)(u16)dv[j] == l15) ? 0x3F80 : 0);
            a2[fi] = t;
        }
        __syncthreads();   // all frag reads done -> next stage may overwrite

        for (int ci = 0; ci < nchunk; ++ci) {
            const int c = wave + ci * 4;
            const int fbase = c * 16;
            short8 wf[5];
#pragma unroll
            for (int ks = 0; ks < 5; ++ks)       // W rows from L1/L2 (hot)
                wf[ks] = *reinterpret_cast<const short8*>(
                    Wm_bf + (size_t)(fbase + l15) * MSG_DIM + ks * 32 + qd * 8);
            const float bias = biasv[ci];
#pragma unroll
            for (int s = 0; s < 4; ++s) {        // 16-edge subtiles
                float4v acc = {0.f, 0.f, 0.f, 0.f};
#pragma unroll
                for (int ks = 0; ks < 5; ++ks)
                    acc = __builtin_amdgcn_mfma_f32_16x16x32_bf16(xf[s][ks], wf[ks], acc, 0, 0, 0);
                // D[e=qd*4+r][f=fbase+l15]; bias+leaky (leaky == max(x, a*x))
                float v0 = acc[0] + bias, v1 = acc[1] + bias,
                      v2 = acc[2] + bias, v3 = acc[3] + bias;
                v0 = fmaxf(v0, ALPHA * v0); v1 = fmaxf(v1, ALPHA * v1);
                v2 = fmaxf(v2, ALPHA * v2); v3 = fmaxf(v3, ALPHA * v3);
                ushort4 m4;
                m4.x = f2bf(v0); m4.y = f2bf(v1); m4.z = f2bf(v2); m4.w = f2bf(v3);
                // transpose via wave-private LDS: MT[f=l15][e=s*16+qd*4 ..+3]
                *reinterpret_cast<ushort4*>(&MTw[l15 * MT_STRIDE + s * 16 + qd * 4]) = m4;
            }
            // reduce: m_acc += S x M  (B operand: lane=f col, k=edge)
            short8 b2_0 = *reinterpret_cast<const short8*>(&MTw[l15 * MT_STRIDE + qd * 8]);
            short8 b2_1 = *reinterpret_cast<const short8*>(&MTw[l15 * MT_STRIDE + 32 + qd * 8]);
            m_acc[ci] = __builtin_amdgcn_mfma_f32_16x16x32_bf16(a2[0], b2_0, m_acc[ci], 0, 0, 0);
            m_acc[ci] = __builtin_amdgcn_mfma_f32_16x16x32_bf16(a2[1], b2_1, m_acc[ci], 0, 0, 0);
        }
    }
    __syncthreads();       // phase-1 X_lds use complete

    // ---------------- phase 2: write m_acc -> bf16 LDS, update GEMM ----------
    u16* Xb = X_lds;       // reuse as [16 nodes][A_STRIDE] bf16
    for (int ci = 0; ci < nchunk; ++ci) {
        const int c = wave + ci * 4;
#pragma unroll
        for (int r = 0; r < 4; ++r)            // D[n=qd*4+r][f=c*16+l15]
            Xb[(qd * 4 + r) * A_STRIDE + c * 16 + l15] = f2bf(m_acc[ci][r]);
    }
    __syncthreads();

    const int node = n0 + l15;                 // exact (50000 = 3125*16)
    short8 b_frag[7];
#pragma unroll
    for (int ks = 0; ks < 5; ++ks)             // k in [0,160): m_sum (bf16)
        b_frag[ks] = *reinterpret_cast<const short8*>(
            &Xb[l15 * A_STRIDE + ks * 32 + qd * 8]);
#pragma unroll
    for (int ks = 5; ks < 7; ++ks)             // k in [160,224): h_n (bf16)
        b_frag[ks] = *reinterpret_cast<const short8*>(
            hn_bf + (size_t)node * D_NODE + (ks - 5) * 32 + qd * 8);

    for (int c = wave; c < 14; c += 4) {       // waves split 14 feature chunks
        float4v acc = {0.f, 0.f, 0.f, 0.f};
#pragma unroll
        for (int ks = 0; ks < 7; ++ks) {
            short8 a = *reinterpret_cast<const short8*>(
                Wh_bf + (size_t)(c * 16 + l15) * HID_DIM + ks * 32 + qd * 8);
            acc = __builtin_amdgcn_mfma_f32_16x16x32_bf16(a, b_frag[ks], acc, 0, 0, 0);
        }
        const float4 bias = *reinterpret_cast<const float4*>(b_hid + c * 16 + qd * 4);
        float v0 = acc[0] + bias.x, v1 = acc[1] + bias.y,
              v2 = acc[2] + bias.z, v3 = acc[3] + bias.w;
        v0 = fmaxf(v0, ALPHA * v0); v1 = fmaxf(v1, ALPHA * v1);
        v2 = fmaxf(v2, ALPHA * v2); v3 = fmaxf(v3, ALPHA * v3);
        float4 o; o.x = v0; o.y = v1; o.z = v2; o.w = v3;
        *reinterpret_cast<float4*>(&out[(size_t)node * HID_DIM + c * 16 + qd * 4]) = o;
    }
}

extern "C" void kernel_launch(void* const* d_in, const int* in_sizes, int n_in,
                              void* d_out, int out_size, void* d_ws, size_t ws_size,
                              hipStream_t stream)
{
    const float* h_n   = (const float*)d_in[0];
    const float* h_e   = (const float*)d_in[1];
    const int*   src   = (const int*)d_in[2];
    const int*   dst   = (const int*)d_in[3];
    const float* W_msg = (const float*)d_in[4];
    const float* b_msg = (const float*)d_in[5];
    const float* W_hid = (const float*)d_in[6];
    const float* b_hid = (const float*)d_in[7];
    float* out = (float*)d_out;

    char* ws = (char*)d_ws;
    u16* hn_bf   = (u16*)(ws + 0);                   //  6,400,000 B
    u16* Wm_bf   = (u16*)(ws + 6400000);             //     51,200 B
    u16* Wh_bf   = (u16*)(ws + 6451200);             //    100,352 B
    int* cnt     = (int*)(ws + 6551552);             //    200,000 B
    int* bkt_ptr = (int*)(ws + 6751552);             //     12,512 B
    int* cursor  = (int*)(ws + 6764064);             //    200,000 B (3125 x 16 ints)
    u64* pack    = (u64*)(ws + 6964064);             //  4,000,000 B  (~11 MB total)

    hipMemsetAsync(cnt, 0, (size_t)N_NODES * sizeof(int), stream);
    cvt_hist<<<CVT_BLKS + HIST_BLKS, 256, 0, stream>>>(
        h_n, W_msg, W_hid, dst, hn_bf, Wm_bf, Wh_bf, cnt);
    scan_kernel<<<1, 1024, 0, stream>>>(cnt, bkt_ptr, cursor);
    scatter_kernel<<<HIST_BLKS, 256, 0, stream>>>(src, dst, cursor, pack);
    fused_kernel<<<NBKT, 256, 0, stream>>>(
        hn_bf, h_e, pack, bkt_ptr, Wm_bf, b_msg, Wh_bf, b_hid, out);
}